// Round 4
// baseline (680.765 us; speedup 1.0000x reference)
//
#include <hip/hip_runtime.h>
#include <hip/hip_bf16.h>

#define Bn 8
#define Nn 256
#define Fn 128
#define Dn 128

typedef __bf16 bf16_t;
typedef bf16_t bf16x8 __attribute__((ext_vector_type(8)));
typedef bf16_t bf16x4 __attribute__((ext_vector_type(4)));
typedef float f32x4 __attribute__((ext_vector_type(4)));

#define GLOAD16(g, l) __builtin_amdgcn_global_load_lds(                        \
    (const __attribute__((address_space(1))) void*)(g),                        \
    (__attribute__((address_space(3))) void*)(l), 16, 0, 0)

// ---------------------------------------------------------------------------
// Fused [rows x 256] x [256 x 128] GEMMs, A = [X1 | X2] concat on k.
// fp32 in/out; bf16 MFMA 16x16x32 with fp32 accumulate.
//
// Round-4: PERSISTENT 4-TILE BLOCKS. BW has been pinned at ~2.8 TB/s across
// four different issue structures -> not a queue-depth problem. r3's shape
// (128 KB LDS = 1 block/CU, one-shot blocks) serializes 8 full block
// lifecycles per CU: prologue (W stage + barrier, drains vmcnt to 0),
// barrier-induced wave lockstep (bursty load issue), bare epilogue drain --
// with nothing resident to overlap any of it.
//
// Now each block does 4 row-tiles: W staged once per 4 tiles, NO barrier
// after the first one (A-chunk buffers are wave-private, W read-only), so
// waves desynchronize across tiles and the CU issues loads continuously.
// Tile t's stores are issued after tile t+1's first two chunk-prefetches ->
// store latency + tile seam hide in the prefetch shadow. One endpgm drain
// per 4 tiles. vmcnt discipline spans the seam (FIFO retirement, m135):
// uniform vmcnt(2); vmcnt(0) only at the very last chunk of the last tile.
//
// 1024 threads = 16 waves x 16 rows/tile. LDS = 64 KB W (bf16, swizzled) +
// 16 waves x 2 x 2 KB A chunk double-buffer = 128 KB.
// ---------------------------------------------------------------------------
__global__ __launch_bounds__(1024, 4) void mfma_gemm_kernel(
    const float* __restrict__ edge, const float* __restrict__ ehid,
    const float* __restrict__ We,   const float* __restrict__ be,
    const float* __restrict__ node, const float* __restrict__ hidden,
    const float* __restrict__ W_m1, const float* __restrict__ b_m1,
    const float* __restrict__ W_m2, const float* __restrict__ b_m2,
    const float* __restrict__ W_o1, const float* __restrict__ b_o1,
    float* __restrict__ out_et,
    float* __restrict__ ws_m1, float* __restrict__ ws_m2, float* __restrict__ ws_h1)
{
    __shared__ __align__(16) char smem[131072];
    bf16_t* wlds = (bf16_t*)smem;               // 64 KB: W bf16, swizzled
    float*  albs = (float*)(smem + 65536);      // 64 KB: A chunks, 16w x 2 x 512 f

    const int t = threadIdx.x;

    // ---- job select (block-uniform). Blocks 0..5: node jobs (2 blocks per
    // weight set x 4 tiles = 8 tiles/set). Blocks 6..517: edge, 4 tiles each.
    const float *X1, *X2, *W, *bias;
    float* out;
    long rowbase0;                               // tiles at rowbase0 + tile*256
    bool streaming;
    if (blockIdx.x >= 6) {
        X1 = edge; X2 = ehid; W = We; bias = be; out = out_et;
        rowbase0 = (long)(blockIdx.x - 6) * 1024;
        streaming = true;                        // output never re-read
    } else {
        const int e = blockIdx.x;
        const int w = e >> 1;
        rowbase0 = (long)(e & 1) * 1024;
        X1 = node; X2 = hidden; streaming = false;
        if (w == 0)      { W = W_m2; bias = b_m2; out = ws_m2; }
        else if (w == 1) { W = W_m1; bias = b_m1; out = ws_m1; }
        else             { W = W_o1; bias = b_o1; out = ws_h1; }
    }

    const int wv     = t >> 6;        // 0..15
    const int l      = t & 63;
    const int lane16 = l & 15;
    const int quad   = l >> 4;

    // per-lane A gather pattern (pre-swizzled source -> swizzled linear LDS):
    // slot s holds A[row = s>>3][kgrp = (s&7) ^ (row&7)] (4 floats)
    const int arow0 = l >> 3;                      // 0..7 (2nd instr: +8)
    const int akg   = (l & 7) ^ (arow0 & 7);
    const long laneoff = ((long)(wv * 16 + arow0)) * 128 + akg * 4;
    const float* aX1 = X1 + rowbase0 * 128 + laneoff;
    const float* aX2 = X2 + rowbase0 * 128 + laneoff;
    float* abw = albs + wv * 1024;                 // wave region: 2 x 512 floats

    const long TSTR = 256 * 128;                   // tile stride in floats

    // issue chunk c (k in [c*32,c*32+32)) of the tile at (x1,x2) into buf b:
    // 2 x global_load_lds, each 8 rows x 32 k (64 lanes x 16 B = 1 KB)
#define ISSUE_CHUNK(x1, x2, c_, b_) do {                                      \
        const float* s_ = ((c_) < 4) ? ((x1) + (c_) * 32)                     \
                                     : ((x2) + ((c_) - 4) * 32);              \
        float* d_ = abw + (b_) * 512;                                         \
        GLOAD16(s_,        d_);                                               \
        GLOAD16(s_ + 1024, d_ + 256);   /* rows +8 = +8*128 floats */         \
    } while (0)

    // prologue: tile 0 chunks 0,1 in flight; latency hides under W staging
    ISSUE_CHUNK(aX1, aX2, 0, 0);
    ISSUE_CHUNK(aX1, aX2, 1, 1);

    // ---- stage W (fp32 global -> bf16 LDS, swizzled), once per block ----
    // element W[k][n] at wlds[n*256 + cp*8 + (k&7)], cp = (k>>3)^(n&7)^((n>>3)&7)
    {
        const int kb4 = t >> 4;            // 0..63 -> k0 = kb4*4
        const int g   = t & 15;            // n-oct
        const int k0  = kb4 * 4;
        const float* wp = W + (long)k0 * 128 + g * 8;
        f32x4 a0[4], a1[4];
        #pragma unroll
        for (int r = 0; r < 4; ++r) {
            a0[r] = *(const f32x4*)(wp + r * 128);
            a1[r] = *(const f32x4*)(wp + r * 128 + 4);
        }
        #pragma unroll
        for (int j = 0; j < 8; ++j) {
            const int n  = g * 8 + j;
            const int cp = (kb4 >> 1) ^ j ^ (g & 7);
            bf16x4 v;
            #pragma unroll
            for (int r = 0; r < 4; ++r)
                v[r] = (bf16_t)(j < 4 ? a0[r][j] : a1[r][j - 4]);
            *(bf16x4*)(&wlds[n * 256 + cp * 8 + (k0 & 7)]) = v;
        }
    }
    __syncthreads();       // the ONLY barrier; waves free-run from here

    float bev[8];
    #pragma unroll
    for (int nt = 0; nt < 8; ++nt) bev[nt] = bias[nt * 16 + lane16];

    // A-read offsets (swizzled): row = lane16, kgrps {quad*2, quad*2+1}
    const int kst0 = (quad * 2)     ^ (lane16 & 7);
    const int kst1 = (quad * 2 + 1) ^ (lane16 & 7);

    for (int tile = 0; tile < 4; ++tile) {
        const float* cX1 = aX1 + tile * TSTR;
        const float* cX2 = aX2 + tile * TSTR;
        const float* nX1 = cX1 + TSTR;
        const float* nX2 = cX2 + TSTR;
        const bool   lastt = (tile == 3);

        f32x4 acc[8];
        #pragma unroll
        for (int nt = 0; nt < 8; ++nt) acc[nt] = (f32x4){0.f, 0.f, 0.f, 0.f};

        #pragma unroll
        for (int c = 0; c < 8; ++c) {
            const int b = c & 1;

            // counted wait: chunks retire FIFO; keep 2 instrs (next chunk)
            // in flight. Only the final chunk of the final tile drains to 0.
            if (lastt && c == 7) asm volatile("s_waitcnt vmcnt(0)" ::: "memory");
            else                 asm volatile("s_waitcnt vmcnt(2)" ::: "memory");
            __builtin_amdgcn_sched_barrier(0);

            const float* bufp = abw + b * 512 + lane16 * 32;
            f32x4 u0 = *(const f32x4*)(bufp + kst0 * 4);
            f32x4 u1 = *(const f32x4*)(bufp + kst1 * 4);
            bf16x8 afrag;
            #pragma unroll
            for (int j = 0; j < 4; ++j) {
                afrag[j]     = (bf16_t)u0[j];
                afrag[j + 4] = (bf16_t)u1[j];
            }

            // WAR fence: A ds_reads must retire before buf b is overwritten
            asm volatile("s_waitcnt lgkmcnt(0)" ::: "memory");
            __builtin_amdgcn_sched_barrier(0);
            if (c < 6)        ISSUE_CHUNK(cX1, cX2, c + 2, b);
            else if (!lastt)  ISSUE_CHUNK(nX1, nX2, c - 6, b);  // next tile c0,c1

            #pragma unroll
            for (int nt = 0; nt < 8; ++nt) {
                const int n    = nt * 16 + lane16;
                const int cidx = c * 4 + quad;
                const int cp   = cidx ^ (n & 7) ^ ((n >> 3) & 7);
                bf16x8 bfrag = *(const bf16x8*)(&wlds[n * 256 + cp * 8]);
                acc[nt] = __builtin_amdgcn_mfma_f32_16x16x32_bf16(afrag, bfrag, acc[nt], 0, 0, 0);
            }
        }

        // store tile (issued AFTER next tile's chunk 0,1 -> hides in their
        // latency shadow; the seam's vmcnt(2) drains these stores cheaply)
        // D layout: col = lane&15, row = quad*4 + reg
        const long orow0 = rowbase0 + tile * 256 + wv * 16 + quad * 4;
        #pragma unroll
        for (int nt = 0; nt < 8; ++nt) {
            #pragma unroll
            for (int r = 0; r < 4; ++r) {
                const float v = acc[nt][r] + bev[nt];
                float* p = out + (orow0 + r) * 128 + nt * 16 + lane16;
                if (streaming) __builtin_nontemporal_store(v, p);
                else           *p = v;
            }
        }
    }
#undef ISSUE_CHUNK
}

// ---------------------------------------------------------------------------
// per (b,j):  mx[d] = max(b_m2[d], max_{i: adj[b,i,j]>0} m2[b,i,d])
//             ret   = h1[b,j,d] + b_o2[d] + sum_k (m1[b,j,k]+mx[k]) * W_o2[k][d]
// 256 threads: 8 i-slices x 32-lane d-groups, f32x4 loads, LDS tree-reduce,
// 2-way k-split GEMV. (unchanged)
// ---------------------------------------------------------------------------
__global__ __launch_bounds__(256) void ret_kernel(
    const int* __restrict__ adj,
    const float* __restrict__ m2, const float* __restrict__ m1,
    const float* __restrict__ h1,
    const float* __restrict__ W_o2, const float* __restrict__ b_o2,
    const float* __restrict__ b_m2,
    float* __restrict__ out)
{
    __shared__ int   adjc[256];
    __shared__ float part[8][128];
    __shared__ float sv[128];

    const int bj = blockIdx.x;       // b*N + j
    const int b  = bj >> 8;
    const int j  = bj & 255;
    const int t  = threadIdx.x;      // 0..255

    adjc[t] = adj[(b * 256 + t) * 256 + j];
    __syncthreads();

    const int s  = t >> 5;           // 0..7
    const int dg = t & 31;           // 0..31
    f32x4 mx4;
    mx4[0] = mx4[1] = mx4[2] = mx4[3] = -3.0e38f;
    const float* m2p = m2 + ((long)b * 256 + s * 32) * 128 + dg * 4;
    #pragma unroll 8
    for (int i = 0; i < 32; ++i) {
        const f32x4 v = *(const f32x4*)(m2p + i * 128);
        const bool on = (adjc[s * 32 + i] != 0);
        mx4[0] = on ? fmaxf(mx4[0], v[0]) : mx4[0];
        mx4[1] = on ? fmaxf(mx4[1], v[1]) : mx4[1];
        mx4[2] = on ? fmaxf(mx4[2], v[2]) : mx4[2];
        mx4[3] = on ? fmaxf(mx4[3], v[3]) : mx4[3];
    }
    *(f32x4*)&part[s][dg * 4] = mx4;
    __syncthreads();

    if (t < 128) {
        float m = b_m2[t];           // virtual node (always connected, zero feats)
        #pragma unroll
        for (int ss = 0; ss < 8; ++ss) m = fmaxf(m, part[ss][t]);
        sv[t] = m1[bj * 128 + t] + m;
    }
    __syncthreads();

    const int d = t & 127;
    const int h = t >> 7;
    float r = 0.f;
    const float* wp = W_o2 + (h * 64) * 128 + d;
    #pragma unroll 8
    for (int k = 0; k < 64; ++k)
        r += sv[h * 64 + k] * wp[k * 128];

    if (h == 1) part[0][d] = r;
    __syncthreads();
    if (h == 0)
        out[bj * 128 + d] = r + part[0][d] + h1[bj * 128 + d] + b_o2[d];
}

// ---------------------------------------------------------------------------
extern "C" void kernel_launch(void* const* d_in, const int* in_sizes, int n_in,
                              void* d_out, int out_size, void* d_ws, size_t ws_size,
                              hipStream_t stream)
{
    const float* node   = (const float*)d_in[0];
    const float* edge   = (const float*)d_in[1];
    // d_in[2] graph_fts: unused by the reference
    const int*   adj    = (const int*)d_in[3];
    const float* hidden = (const float*)d_in[4];
    const float* ehid   = (const float*)d_in[5];
    const float* We     = (const float*)d_in[6];
    const float* be     = (const float*)d_in[7];
    const float* W_m1   = (const float*)d_in[8];
    const float* b_m1   = (const float*)d_in[9];
    const float* W_m2   = (const float*)d_in[10];
    const float* b_m2   = (const float*)d_in[11];
    const float* W_o1   = (const float*)d_in[12];
    const float* b_o1   = (const float*)d_in[13];
    const float* W_o2   = (const float*)d_in[14];
    const float* b_o2   = (const float*)d_in[15];

    float* out_ret = (float*)d_out;                     // [8,256,128]
    float* out_et  = (float*)d_out + Bn * Nn * Dn;      // [8,256,256,128]

    float* ws_m2 = (float*)d_ws;                        // [2048,128]
    float* ws_m1 = ws_m2 + 2048 * 128;
    float* ws_h1 = ws_m1 + 2048 * 128;                  // 3 MB total

    // One fused dispatch: 6 node blocks (first, scheduled in round 0) +
    // 512 edge blocks, each persistent over 4 row-tiles.
    hipLaunchKernelGGL(mfma_gemm_kernel, dim3(518), dim3(1024), 0, stream,
                       edge, ehid, We, be, node, hidden,
                       W_m1, b_m1, W_m2, b_m2, W_o1, b_o1,
                       out_et, ws_m1, ws_m2, ws_h1);
    // adjacency max + output GEMV
    hipLaunchKernelGGL(ret_kernel, dim3(2048), dim3(256), 0, stream,
                       adj, ws_m2, ws_m1, ws_h1, W_o2, b_o2, b_m2, out_ret);
}